// Round 2
// baseline (935.783 us; speedup 1.0000x reference)
//
#include <hip/hip_runtime.h>

#define NPTS 6144
#define RESCALE (1.0f / 1024.0f)

// matvec geometry: 96 i-groups x 64 rows; 32 j-partitions x 192 j (12 tiles of 16)
#define NIG  96
#define MI   4
#define JTL  12

typedef unsigned short u16;
typedef unsigned int   u32;
typedef float v2f    __attribute__((ext_vector_type(2)));
typedef short bf16x8 __attribute__((ext_vector_type(8)));
typedef float f32x4  __attribute__((ext_vector_type(4)));

// Truncating bf16 split: returns top-16 bits, leaves exact residual in x.
__device__ __forceinline__ u16 bsplit(float& x) {
  u32 u = __float_as_uint(x) & 0xFFFF0000u;
  x -= __uint_as_float(u);
  return (u16)(u >> 16);
}
__device__ __forceinline__ u32 pk(u16 lo, u16 hi) { return (u32)lo | ((u32)hi << 16); }

// Per point, build MFMA fragment rows (k-major, 32 bf16 each) for:
//   a(i,j) = |p2_i - p2_j|^2 = n2_i + n2_j - 2<p2_i,p2_j>   (A2 row x B2 row, K=18 used)
//   b(i,j) = |p3_i - p3_j|^2                                  (A3 row x B3 row, K=24 used)
// 3-way bf16 truncation splits (h,m,l) with products hh,mh,hm,mm,lh,hl kept
// (~2^-24 relative); norms folded in as extra K columns against constant 1.0.
__global__ __launch_bounds__(256) void prep_kernel(
    const float* __restrict__ p2, const float* __restrict__ p3,
    u32* __restrict__ A2, u32* __restrict__ B2,
    u32* __restrict__ A3, u32* __restrict__ B3,
    float* __restrict__ vA, float* __restrict__ vB) {
  int i = blockIdx.x * 256 + threadIdx.x;
  if (i >= NPTS) return;
  float x2 = p2[2 * i], y2 = p2[2 * i + 1];
  float x3 = p3[3 * i], y3 = p3[3 * i + 1], z3 = p3[3 * i + 2];
  float n2 = fmaf(x2, x2, y2 * y2);
  float n3 = fmaf(x3, x3, fmaf(y3, y3, z3 * z3));
  const u16 ONE = 0x3F80;  // bf16(1.0)
  float t;
  t = -2.f * x2; u16 AXH = bsplit(t), AXM = bsplit(t), AXL = bsplit(t);
  t = -2.f * y2; u16 AYH = bsplit(t), AYM = bsplit(t), AYL = bsplit(t);
  t = x2;        u16 BXH = bsplit(t), BXM = bsplit(t), BXL = bsplit(t);
  t = y2;        u16 BYH = bsplit(t), BYM = bsplit(t), BYL = bsplit(t);
  t = n2;        u16 N2H = bsplit(t), N2M = bsplit(t), N2L = bsplit(t);
  t = -2.f * x3; u16 CXH = bsplit(t), CXM = bsplit(t), CXL = bsplit(t);
  t = -2.f * y3; u16 CYH = bsplit(t), CYM = bsplit(t), CYL = bsplit(t);
  t = -2.f * z3; u16 CZH = bsplit(t), CZM = bsplit(t), CZL = bsplit(t);
  t = x3;        u16 DXH = bsplit(t), DXM = bsplit(t), DXL = bsplit(t);
  t = y3;        u16 DYH = bsplit(t), DYM = bsplit(t), DYL = bsplit(t);
  t = z3;        u16 DZH = bsplit(t), DZM = bsplit(t), DZL = bsplit(t);
  t = n3;        u16 N3H = bsplit(t), N3M = bsplit(t), N3L = bsplit(t);

  u32* a2 = A2 + i * 16;  // k: 2q, 2q+1
  a2[0] = pk(AXH, AYH); a2[1] = pk(AXM, AYM); a2[2] = pk(AXH, AYH); a2[3] = pk(AXM, AYM);
  a2[4] = pk(AXL, AYL); a2[5] = pk(AXH, AYH); a2[6] = pk(N2H, N2M); a2[7] = pk(N2L, ONE);
  a2[8] = pk(ONE, ONE);
#pragma unroll
  for (int q = 9; q < 16; ++q) a2[q] = 0u;

  u32* b2 = B2 + i * 16;
  b2[0] = pk(BXH, BYH); b2[1] = pk(BXH, BYH); b2[2] = pk(BXM, BYM); b2[3] = pk(BXM, BYM);
  b2[4] = pk(BXH, BYH); b2[5] = pk(BXL, BYL); b2[6] = pk(ONE, ONE); b2[7] = pk(ONE, N2H);
  b2[8] = pk(N2M, N2L);
#pragma unroll
  for (int q = 9; q < 16; ++q) b2[q] = 0u;

  u32* a3 = A3 + i * 16;
  a3[0] = pk(CXH, CYH); a3[1]  = pk(CZH, CXM); a3[2]  = pk(CYM, CZM); a3[3]  = pk(CXH, CYH);
  a3[4] = pk(CZH, CXM); a3[5]  = pk(CYM, CZM); a3[6]  = pk(CXL, CYL); a3[7]  = pk(CZL, CXH);
  a3[8] = pk(CYH, CZH); a3[9]  = pk(N3H, N3M); a3[10] = pk(N3L, ONE); a3[11] = pk(ONE, ONE);
#pragma unroll
  for (int q = 12; q < 16; ++q) a3[q] = 0u;

  u32* b3 = B3 + i * 16;
  b3[0] = pk(DXH, DYH); b3[1]  = pk(DZH, DXH); b3[2]  = pk(DYH, DZH); b3[3]  = pk(DXM, DYM);
  b3[4] = pk(DZM, DXM); b3[5]  = pk(DYM, DZM); b3[6]  = pk(DXH, DYH); b3[7]  = pk(DZH, DXL);
  b3[8] = pk(DYL, DZL); b3[9]  = pk(ONE, ONE); b3[10] = pk(ONE, N3H); b3[11] = pk(N3M, N3L);
#pragma unroll
  for (int q = 12; q < 16; ++q) b3[q] = 0u;

  vA[i] = 1.0f;  // v0 = ones
  vB[i] = 0.0f;  // iter0 atomic target
}

// y[i] += (1/1024) * sum_j S(i,j) v[j].  Each wave: 64 i-rows (4 16x16 tiles)
// x 192 j (12 tiles). Per tile: 2 MFMAs give a,b; VALU does
// S = max(0, 1 - 100(a+b) + 200*sqrt(max(ab,0))) and acc += S*v_j.
// Epilogue: 16-lane shuffle column-reduce, 64 atomics/wave (12x fewer than before).
__global__ __launch_bounds__(256, 3) void matvec_kernel(
    const u16* __restrict__ A2, const u16* __restrict__ B2,
    const u16* __restrict__ A3, const u16* __restrict__ B3,
    const float* __restrict__ vsrc, float* __restrict__ vdst,
    float* __restrict__ vzero) {
  const int igrp = blockIdx.x >> 3;   // 0..95
  const int jpg  = blockIdx.x & 7;    // 0..7
  const int lane = threadIdx.x & 63;
  const int wv   = threadIdx.x >> 6;
  const int jp   = jpg * 4 + wv;      // 0..31
  const int col  = lane & 15;
  const int kb   = lane >> 4;         // 0..3 (k-block of 8)

  if (jpg == 0 && threadIdx.x < 64) vzero[igrp * 64 + threadIdx.x] = 0.0f;

  // A-side fragments: row = igrp*64 + mi*16 + (lane&15), k = kb*8..kb*8+7
  bf16x8 a2f[MI], a3f[MI];
#pragma unroll
  for (int mi = 0; mi < MI; ++mi) {
    const int r = igrp * 64 + mi * 16 + col;
    a2f[mi] = *(const bf16x8*)(A2 + r * 32 + kb * 8);
    a3f[mi] = *(const bf16x8*)(A3 + r * 32 + kb * 8);
  }

  v2f racc[MI][2];
#pragma unroll
  for (int mi = 0; mi < MI; ++mi) {
    racc[mi][0] = (v2f){0.f, 0.f};
    racc[mi][1] = (v2f){0.f, 0.f};
  }

  const v2f kM100 = (v2f){-100.0f, -100.0f};
  const v2f k200  = (v2f){ 200.0f,  200.0f};
  const v2f kOne  = (v2f){   1.0f,    1.0f};
  const v2f kZero = (v2f){   0.0f,    0.0f};
  const f32x4 z4  = (f32x4){0.f, 0.f, 0.f, 0.f};

  const int j0 = jp * (JTL * 16);
  for (int tj = 0; tj < JTL; ++tj) {
    const int jc = j0 + tj * 16 + col;
    const bf16x8 b2f = *(const bf16x8*)(B2 + jc * 32 + kb * 8);
    const bf16x8 b3f = *(const bf16x8*)(B3 + jc * 32 + kb * 8);
    const float vjs = vsrc[jc];
    const v2f vj2 = (v2f){vjs, vjs};
#pragma unroll
    for (int mi = 0; mi < MI; ++mi) {
      f32x4 aacc = __builtin_amdgcn_mfma_f32_16x16x32_bf16(a2f[mi], b2f, z4, 0, 0, 0);
      f32x4 bacc = __builtin_amdgcn_mfma_f32_16x16x32_bf16(a3f[mi], b3f, z4, 0, 0, 0);
#pragma unroll
      for (int p = 0; p < 2; ++p) {
        v2f a = (v2f){aacc[2 * p], aacc[2 * p + 1]};
        v2f b = (v2f){bacc[2 * p], bacc[2 * p + 1]};
        v2f ab = __builtin_elementwise_max(a * b, kZero);  // NaN guard (diagonal: a,b ~ +-eps)
        v2f s  = (v2f){__builtin_amdgcn_sqrtf(ab.x), __builtin_amdgcn_sqrtf(ab.y)};
        v2f w  = __builtin_elementwise_fma(a + b, kM100, kOne);
        w = __builtin_elementwise_fma(s, k200, w);
        w = __builtin_elementwise_max(w, kZero);
        racc[mi][p] = __builtin_elementwise_fma(w, vj2, racc[mi][p]);
      }
    }
  }

  // Column reduce within each 16-lane group (cols of the tile), then atomics.
#pragma unroll
  for (int mi = 0; mi < MI; ++mi) {
#pragma unroll
    for (int p = 0; p < 2; ++p) {
      float r0 = racc[mi][p].x, r1 = racc[mi][p].y;
      r0 += __shfl_xor(r0, 1); r0 += __shfl_xor(r0, 2);
      r0 += __shfl_xor(r0, 4); r0 += __shfl_xor(r0, 8);
      r1 += __shfl_xor(r1, 1); r1 += __shfl_xor(r1, 2);
      r1 += __shfl_xor(r1, 4); r1 += __shfl_xor(r1, 8);
      if (col == 0) {
        const int row = igrp * 64 + mi * 16 + kb * 4 + 2 * p;  // D: row=(lane>>4)*4+reg
        atomicAdd(&vdst[row],     r0 * RESCALE);
        atomicAdd(&vdst[row + 1], r1 * RESCALE);
      }
    }
  }
}

// out = v / (||v||_2 + 1e-6); each block redundantly computes the norm.
__global__ __launch_bounds__(256) void finalize_kernel(
    const float* __restrict__ v, float* __restrict__ out) {
  const int tid = threadIdx.x;
  float ss = 0.0f;
  for (int k = tid; k < NPTS; k += 256) {
    float x = v[k];
    ss = fmaf(x, x, ss);
  }
  for (int off = 32; off > 0; off >>= 1) ss += __shfl_down(ss, off, 64);
  __shared__ float wsum[4];
  if ((tid & 63) == 0) wsum[tid >> 6] = ss;
  __syncthreads();
  float tot = wsum[0] + wsum[1] + wsum[2] + wsum[3];
  float inv = 1.0f / (sqrtf(tot) + 1e-6f);
  int i = blockIdx.x * 256 + tid;
  out[i] = v[i] * inv;
}

extern "C" void kernel_launch(void* const* d_in, const int* in_sizes, int n_in,
                              void* d_out, int out_size, void* d_ws, size_t ws_size,
                              hipStream_t stream) {
  const float* p2 = (const float*)d_in[0];   // 6144 x 2, float32
  const float* p3 = (const float*)d_in[1];   // 6144 x 3, float32
  float* out = (float*)d_out;                // 6144, float32

  float* w = (float*)d_ws;
  float* buf[3] = { w, w + 8192, w + 16384 };      // v triple-buffer
  u32* fr = (u32*)(w + 24576);                     // 16B-aligned fragment arrays
  u32* A2 = fr;
  u32* B2 = fr + NPTS * 16;
  u32* A3 = fr + NPTS * 16 * 2;
  u32* B3 = fr + NPTS * 16 * 3;

  prep_kernel<<<NPTS / 256, 256, 0, stream>>>(p2, p3, A2, B2, A3, B3, buf[0], buf[1]);

  for (int k = 0; k < 10; ++k) {
    matvec_kernel<<<NIG * 8, 256, 0, stream>>>(
        (const u16*)A2, (const u16*)B2, (const u16*)A3, (const u16*)B3,
        buf[k % 3], buf[(k + 1) % 3], buf[(k + 2) % 3]);
  }

  // after 10 iters, result is in buf[(9+1)%3] == buf[1]
  finalize_kernel<<<NPTS / 256, 256, 0, stream>>>(buf[1], out);
}

// Round 3
// 237.977 us; speedup vs baseline: 3.9322x; 3.9322x over previous
//
#include <hip/hip_runtime.h>

#define NPTS 6144
#define RESCALE (1.0f / 1024.0f)

// matvec geometry: 24 i-blocks x 24 j-blocks (256x256 tile per block, 4 waves).
// Wave wv owns 64 i-rows (4 MFMA row-tiles); all waves share the block's 256 j.
#define NIB 24
#define NJB 24
#define BI  256
#define BJ  256
#define MI  4
#define JT  (BJ / 16)     // 16 j-tiles
#define ROWU 20           // u32 stride per fragment row (16 + 4 pad -> 2-way banks)
#define LDS_U32 (2 * BJ * ROWU + BJ)  // B2 | B3 | v  (phase 1 reuses as A2 | A3)

typedef unsigned short u16;
typedef unsigned int   u32;
typedef float v2f    __attribute__((ext_vector_type(2)));
typedef short bf16x8 __attribute__((ext_vector_type(8)));
typedef float f32x4  __attribute__((ext_vector_type(4)));

// Truncating bf16 split: returns top-16 bits, leaves exact residual in x.
__device__ __forceinline__ u16 bsplit(float& x) {
  u32 u = __float_as_uint(x) & 0xFFFF0000u;
  x -= __uint_as_float(u);
  return (u16)(u >> 16);
}
__device__ __forceinline__ u32 pk(u16 lo, u16 hi) { return (u32)lo | ((u32)hi << 16); }

// Fragment packing (verified on HW in round 2, absmax 6.1e-5):
//   a(i,j) = |p2_i-p2_j|^2 = n2_i + n2_j - 2<p2_i,p2_j>  via 3-way bf16 splits,
//   products {hh,mh,hm,mm,lh,hl} + norm slots, K=18 of 32 used (2D) / 24 (3D).
__device__ __forceinline__ void build_i(float x2, float y2, float x3, float y3,
                                        float z3, u32* __restrict__ a2,
                                        u32* __restrict__ a3) {
  float n2 = fmaf(x2, x2, y2 * y2);
  float n3 = fmaf(x3, x3, fmaf(y3, y3, z3 * z3));
  const u16 ONE = 0x3F80;
  float t;
  t = -2.f * x2; u16 AXH = bsplit(t), AXM = bsplit(t), AXL = bsplit(t);
  t = -2.f * y2; u16 AYH = bsplit(t), AYM = bsplit(t), AYL = bsplit(t);
  t = n2;        u16 N2H = bsplit(t), N2M = bsplit(t), N2L = bsplit(t);
  t = -2.f * x3; u16 CXH = bsplit(t), CXM = bsplit(t), CXL = bsplit(t);
  t = -2.f * y3; u16 CYH = bsplit(t), CYM = bsplit(t), CYL = bsplit(t);
  t = -2.f * z3; u16 CZH = bsplit(t), CZM = bsplit(t), CZL = bsplit(t);
  t = n3;        u16 N3H = bsplit(t), N3M = bsplit(t), N3L = bsplit(t);
  a2[0] = pk(AXH, AYH); a2[1] = pk(AXM, AYM); a2[2] = pk(AXH, AYH); a2[3] = pk(AXM, AYM);
  a2[4] = pk(AXL, AYL); a2[5] = pk(AXH, AYH); a2[6] = pk(N2H, N2M); a2[7] = pk(N2L, ONE);
  a2[8] = pk(ONE, ONE);
#pragma unroll
  for (int q = 9; q < 16; ++q) a2[q] = 0u;
  a3[0] = pk(CXH, CYH); a3[1]  = pk(CZH, CXM); a3[2]  = pk(CYM, CZM); a3[3]  = pk(CXH, CYH);
  a3[4] = pk(CZH, CXM); a3[5]  = pk(CYM, CZM); a3[6]  = pk(CXL, CYL); a3[7]  = pk(CZL, CXH);
  a3[8] = pk(CYH, CZH); a3[9]  = pk(N3H, N3M); a3[10] = pk(N3L, ONE); a3[11] = pk(ONE, ONE);
#pragma unroll
  for (int q = 12; q < 16; ++q) a3[q] = 0u;
}

__device__ __forceinline__ void build_j(float x2, float y2, float x3, float y3,
                                        float z3, u32* __restrict__ b2,
                                        u32* __restrict__ b3) {
  float n2 = fmaf(x2, x2, y2 * y2);
  float n3 = fmaf(x3, x3, fmaf(y3, y3, z3 * z3));
  const u16 ONE = 0x3F80;
  float t;
  t = x2; u16 BXH = bsplit(t), BXM = bsplit(t), BXL = bsplit(t);
  t = y2; u16 BYH = bsplit(t), BYM = bsplit(t), BYL = bsplit(t);
  t = n2; u16 N2H = bsplit(t), N2M = bsplit(t), N2L = bsplit(t);
  t = x3; u16 DXH = bsplit(t), DXM = bsplit(t), DXL = bsplit(t);
  t = y3; u16 DYH = bsplit(t), DYM = bsplit(t), DYL = bsplit(t);
  t = z3; u16 DZH = bsplit(t), DZM = bsplit(t), DZL = bsplit(t);
  t = n3; u16 N3H = bsplit(t), N3M = bsplit(t), N3L = bsplit(t);
  b2[0] = pk(BXH, BYH); b2[1] = pk(BXH, BYH); b2[2] = pk(BXM, BYM); b2[3] = pk(BXM, BYM);
  b2[4] = pk(BXH, BYH); b2[5] = pk(BXL, BYL); b2[6] = pk(ONE, ONE); b2[7] = pk(ONE, N2H);
  b2[8] = pk(N2M, N2L);
#pragma unroll
  for (int q = 9; q < 16; ++q) b2[q] = 0u;
  b3[0] = pk(DXH, DYH); b3[1]  = pk(DZH, DXH); b3[2]  = pk(DYH, DZH); b3[3]  = pk(DXM, DYM);
  b3[4] = pk(DZM, DXM); b3[5]  = pk(DYM, DZM); b3[6]  = pk(DXH, DYH); b3[7]  = pk(DZH, DXL);
  b3[8] = pk(DYL, DZL); b3[9]  = pk(ONE, ONE); b3[10] = pk(ONE, N3H); b3[11] = pk(N3M, N3L);
#pragma unroll
  for (int q = 12; q < 16; ++q) b3[q] = 0u;
}

__global__ __launch_bounds__(256) void prep_kernel(float* __restrict__ vA,
                                                   float* __restrict__ vB) {
  int i = blockIdx.x * 256 + threadIdx.x;
  vA[i] = 1.0f;   // v0 = ones
  vB[i] = 0.0f;   // iter0 atomic target
}

// y[i] += (1/1024) * sum_j S(i,j) v[j].  Fragments are REBUILT in LDS each
// launch from raw p2/p3 (20 B/point) -- the fragment tables never touch
// global memory, eliminating the 139 MB/dispatch re-fetch seen in round 2.
__global__ __launch_bounds__(256, 2) void matvec_kernel(
    const float* __restrict__ p2, const float* __restrict__ p3,
    const float* __restrict__ vsrc, float* __restrict__ vdst,
    float* __restrict__ vzero) {
  __shared__ u32 sh[LDS_U32];
  float* shf = (float*)sh;
  const int ib = blockIdx.x % NIB;
  const int jb = blockIdx.x / NIB;
  const int t    = threadIdx.x;
  const int lane = t & 63;
  const int wv   = t >> 6;
  const int col  = lane & 15;
  const int kb   = lane >> 4;

  const int ipt = ib * BI + t;
  const int jpt = jb * BJ + t;
  // All global loads issued up front (one latency exposure).
  float ix2 = p2[2 * ipt], iy2 = p2[2 * ipt + 1];
  float ix3 = p3[3 * ipt], iy3 = p3[3 * ipt + 1], iz3 = p3[3 * ipt + 2];
  float jx2 = p2[2 * jpt], jy2 = p2[2 * jpt + 1];
  float jx3 = p3[3 * jpt], jy3 = p3[3 * jpt + 1], jz3 = p3[3 * jpt + 2];
  float vj  = vsrc[jpt];
  if (jb == 0) vzero[ipt] = 0.0f;

  // Phase 1: i-side fragments in LDS, hoist to regs.
  build_i(ix2, iy2, ix3, iy3, iz3, &sh[t * ROWU], &sh[BI * ROWU + t * ROWU]);
  __syncthreads();
  bf16x8 a2f[MI], a3f[MI];
#pragma unroll
  for (int mi = 0; mi < MI; ++mi) {
    const int r = wv * 64 + mi * 16 + col;
    a2f[mi] = *(const bf16x8*)&sh[r * ROWU + kb * 4];
    a3f[mi] = *(const bf16x8*)&sh[BI * ROWU + r * ROWU + kb * 4];
  }
  __syncthreads();
  // Phase 2: j-side fragments + v-slice (overwrites phase-1 region).
  build_j(jx2, jy2, jx3, jy3, jz3, &sh[t * ROWU], &sh[BJ * ROWU + t * ROWU]);
  shf[2 * BJ * ROWU + t] = vj;
  __syncthreads();

  v2f racc[MI][2];
#pragma unroll
  for (int mi = 0; mi < MI; ++mi) {
    racc[mi][0] = (v2f){0.f, 0.f};
    racc[mi][1] = (v2f){0.f, 0.f};
  }
  const v2f kM100 = (v2f){-100.0f, -100.0f};
  const v2f k200  = (v2f){ 200.0f,  200.0f};
  const v2f kOne  = (v2f){   1.0f,    1.0f};
  const v2f kZero = (v2f){   0.0f,    0.0f};
  const f32x4 z4  = (f32x4){0.f, 0.f, 0.f, 0.f};

  for (int tj = 0; tj < JT; ++tj) {
    const int jrow = tj * 16 + col;
    const bf16x8 b2f = *(const bf16x8*)&sh[jrow * ROWU + kb * 4];
    const bf16x8 b3f = *(const bf16x8*)&sh[BJ * ROWU + jrow * ROWU + kb * 4];
    const float vjs = shf[2 * BJ * ROWU + jrow];
    const v2f vj2 = (v2f){vjs, vjs};
#pragma unroll
    for (int mi = 0; mi < MI; ++mi) {
      f32x4 aacc = __builtin_amdgcn_mfma_f32_16x16x32_bf16(a2f[mi], b2f, z4, 0, 0, 0);
      f32x4 bacc = __builtin_amdgcn_mfma_f32_16x16x32_bf16(a3f[mi], b3f, z4, 0, 0, 0);
#pragma unroll
      for (int p = 0; p < 2; ++p) {
        v2f a = (v2f){aacc[2 * p], aacc[2 * p + 1]};
        v2f b = (v2f){bacc[2 * p], bacc[2 * p + 1]};
        v2f ab = __builtin_elementwise_max(a * b, kZero);  // NaN guard near diagonal
        v2f s  = (v2f){__builtin_amdgcn_sqrtf(ab.x), __builtin_amdgcn_sqrtf(ab.y)};
        v2f w  = __builtin_elementwise_fma(a + b, kM100, kOne);
        w = __builtin_elementwise_fma(s, k200, w);
        w = __builtin_elementwise_max(w, kZero);
        racc[mi][p] = __builtin_elementwise_fma(w, vj2, racc[mi][p]);
      }
    }
  }

  // Column reduce within each 16-lane group, then one atomic per row per block.
#pragma unroll
  for (int mi = 0; mi < MI; ++mi) {
#pragma unroll
    for (int p = 0; p < 2; ++p) {
      float r0 = racc[mi][p].x, r1 = racc[mi][p].y;
      r0 += __shfl_xor(r0, 1); r0 += __shfl_xor(r0, 2);
      r0 += __shfl_xor(r0, 4); r0 += __shfl_xor(r0, 8);
      r1 += __shfl_xor(r1, 1); r1 += __shfl_xor(r1, 2);
      r1 += __shfl_xor(r1, 4); r1 += __shfl_xor(r1, 8);
      if (col == 0) {
        const int row = ib * BI + wv * 64 + mi * 16 + kb * 4 + 2 * p;  // D row map
        atomicAdd(&vdst[row],     r0 * RESCALE);
        atomicAdd(&vdst[row + 1], r1 * RESCALE);
      }
    }
  }
}

// out = v / (||v||_2 + 1e-6); each block redundantly computes the norm.
__global__ __launch_bounds__(256) void finalize_kernel(
    const float* __restrict__ v, float* __restrict__ out) {
  const int tid = threadIdx.x;
  float ss = 0.0f;
  for (int k = tid; k < NPTS; k += 256) {
    float x = v[k];
    ss = fmaf(x, x, ss);
  }
  for (int off = 32; off > 0; off >>= 1) ss += __shfl_down(ss, off, 64);
  __shared__ float wsum[4];
  if ((tid & 63) == 0) wsum[tid >> 6] = ss;
  __syncthreads();
  float tot = wsum[0] + wsum[1] + wsum[2] + wsum[3];
  float inv = 1.0f / (sqrtf(tot) + 1e-6f);
  int i = blockIdx.x * 256 + tid;
  out[i] = v[i] * inv;
}

extern "C" void kernel_launch(void* const* d_in, const int* in_sizes, int n_in,
                              void* d_out, int out_size, void* d_ws, size_t ws_size,
                              hipStream_t stream) {
  const float* p2 = (const float*)d_in[0];   // 6144 x 2, float32
  const float* p3 = (const float*)d_in[1];   // 6144 x 3, float32
  float* out = (float*)d_out;                // 6144, float32

  float* w = (float*)d_ws;
  float* buf[3] = { w, w + 8192, w + 16384 };  // v triple-buffer

  prep_kernel<<<NPTS / 256, 256, 0, stream>>>(buf[0], buf[1]);

  for (int k = 0; k < 10; ++k) {
    matvec_kernel<<<NIB * NJB, 256, 0, stream>>>(
        p2, p3, buf[k % 3], buf[(k + 1) % 3], buf[(k + 2) % 3]);
  }

  // after 10 iters, result is in buf[(9+1)%3] == buf[1]
  finalize_kernel<<<NPTS / 256, 256, 0, stream>>>(buf[1], out);
}

// Round 4
// 227.479 us; speedup vs baseline: 4.1137x; 1.0461x over previous
//
#include <hip/hip_runtime.h>

#define NPTS 6144
#define RESCALE (1.0f / 1024.0f)

// Symmetric-triangle matvec: 48 tiles of 128 points; blocks cover ib<=jb only
// (1176 blocks). Off-diagonal blocks emit row- AND column-contributions
// (S is exactly symmetric), halving pair work vs the full grid.
#define NB   48
#define BT   128
#define NBLK (NB * (NB + 1) / 2)   // 1176
#define MI   2                     // row-tiles per wave (32 rows)
#define JT   8                     // j-tiles (128/16)
#define ROWU 20                    // u32 stride per fragment row (16 + 4 pad)
#define OFF_A  0
#define OFF_B  (2 * BT * ROWU)
#define OFF_VJ (4 * BT * ROWU)
#define OFF_VI (4 * BT * ROWU + BT)
#define LDS_U32 (4 * BT * ROWU + 2 * BT)   // 10496 u32 = 41 KB

typedef unsigned short u16;
typedef unsigned int   u32;
typedef float v2f    __attribute__((ext_vector_type(2)));
typedef short bf16x8 __attribute__((ext_vector_type(8)));
typedef float f32x4  __attribute__((ext_vector_type(4)));

// Truncating bf16 split: returns top-16 bits, leaves exact residual in x.
__device__ __forceinline__ u16 bsplit(float& x) {
  u32 u = __float_as_uint(x) & 0xFFFF0000u;
  x -= __uint_as_float(u);
  return (u16)(u >> 16);
}
__device__ __forceinline__ u32 pk(u16 lo, u16 hi) { return (u32)lo | ((u32)hi << 16); }

// Fragment packing (HW-verified rounds 2-3, absmax 6.1e-5):
//   a(i,j) = n2_i + n2_j - 2<p2_i,p2_j> via 3-way bf16 splits (K=18 of 32),
//   b(i,j) likewise for 3D (K=24 of 32).
__device__ __forceinline__ void build_i(float x2, float y2, float x3, float y3,
                                        float z3, u32* __restrict__ a2,
                                        u32* __restrict__ a3) {
  float n2 = fmaf(x2, x2, y2 * y2);
  float n3 = fmaf(x3, x3, fmaf(y3, y3, z3 * z3));
  const u16 ONE = 0x3F80;
  float t;
  t = -2.f * x2; u16 AXH = bsplit(t), AXM = bsplit(t), AXL = bsplit(t);
  t = -2.f * y2; u16 AYH = bsplit(t), AYM = bsplit(t), AYL = bsplit(t);
  t = n2;        u16 N2H = bsplit(t), N2M = bsplit(t), N2L = bsplit(t);
  t = -2.f * x3; u16 CXH = bsplit(t), CXM = bsplit(t), CXL = bsplit(t);
  t = -2.f * y3; u16 CYH = bsplit(t), CYM = bsplit(t), CYL = bsplit(t);
  t = -2.f * z3; u16 CZH = bsplit(t), CZM = bsplit(t), CZL = bsplit(t);
  t = n3;        u16 N3H = bsplit(t), N3M = bsplit(t), N3L = bsplit(t);
  a2[0] = pk(AXH, AYH); a2[1] = pk(AXM, AYM); a2[2] = pk(AXH, AYH); a2[3] = pk(AXM, AYM);
  a2[4] = pk(AXL, AYL); a2[5] = pk(AXH, AYH); a2[6] = pk(N2H, N2M); a2[7] = pk(N2L, ONE);
  a2[8] = pk(ONE, ONE);
#pragma unroll
  for (int q = 9; q < 16; ++q) a2[q] = 0u;
  a3[0] = pk(CXH, CYH); a3[1]  = pk(CZH, CXM); a3[2]  = pk(CYM, CZM); a3[3]  = pk(CXH, CYH);
  a3[4] = pk(CZH, CXM); a3[5]  = pk(CYM, CZM); a3[6]  = pk(CXL, CYL); a3[7]  = pk(CZL, CXH);
  a3[8] = pk(CYH, CZH); a3[9]  = pk(N3H, N3M); a3[10] = pk(N3L, ONE); a3[11] = pk(ONE, ONE);
#pragma unroll
  for (int q = 12; q < 16; ++q) a3[q] = 0u;
}

__device__ __forceinline__ void build_j(float x2, float y2, float x3, float y3,
                                        float z3, u32* __restrict__ b2,
                                        u32* __restrict__ b3) {
  float n2 = fmaf(x2, x2, y2 * y2);
  float n3 = fmaf(x3, x3, fmaf(y3, y3, z3 * z3));
  const u16 ONE = 0x3F80;
  float t;
  t = x2; u16 BXH = bsplit(t), BXM = bsplit(t), BXL = bsplit(t);
  t = y2; u16 BYH = bsplit(t), BYM = bsplit(t), BYL = bsplit(t);
  t = n2; u16 N2H = bsplit(t), N2M = bsplit(t), N2L = bsplit(t);
  t = x3; u16 DXH = bsplit(t), DXM = bsplit(t), DXL = bsplit(t);
  t = y3; u16 DYH = bsplit(t), DYM = bsplit(t), DYL = bsplit(t);
  t = z3; u16 DZH = bsplit(t), DZM = bsplit(t), DZL = bsplit(t);
  t = n3; u16 N3H = bsplit(t), N3M = bsplit(t), N3L = bsplit(t);
  b2[0] = pk(BXH, BYH); b2[1] = pk(BXH, BYH); b2[2] = pk(BXM, BYM); b2[3] = pk(BXM, BYM);
  b2[4] = pk(BXH, BYH); b2[5] = pk(BXL, BYL); b2[6] = pk(ONE, ONE); b2[7] = pk(ONE, N2H);
  b2[8] = pk(N2M, N2L);
#pragma unroll
  for (int q = 9; q < 16; ++q) b2[q] = 0u;
  b3[0] = pk(DXH, DYH); b3[1]  = pk(DZH, DXH); b3[2]  = pk(DYH, DZH); b3[3]  = pk(DXM, DYM);
  b3[4] = pk(DZM, DXM); b3[5]  = pk(DYM, DZM); b3[6]  = pk(DXH, DYH); b3[7]  = pk(DZH, DXL);
  b3[8] = pk(DYL, DZL); b3[9]  = pk(ONE, ONE); b3[10] = pk(ONE, N3H); b3[11] = pk(N3M, N3L);
#pragma unroll
  for (int q = 12; q < 16; ++q) b3[q] = 0u;
}

__global__ __launch_bounds__(256) void prep_kernel(float* __restrict__ vA,
                                                   float* __restrict__ vB) {
  int i = blockIdx.x * 256 + threadIdx.x;
  vA[i] = 1.0f;   // v0 = ones
  vB[i] = 0.0f;   // iter0 atomic target
}

// y += (1/1024) * S v over the block's (ib,jb) 128x128 tile, ib<=jb.
// One barrier: waves 0-1 build i-side fragments, waves 2-3 build j-side.
__global__ __launch_bounds__(256, 3) void matvec_kernel(
    const float* __restrict__ p2, const float* __restrict__ p3,
    const float* __restrict__ vsrc, float* __restrict__ vdst,
    float* __restrict__ vzero) {
  __shared__ u32 sh[LDS_U32];
  float* shf = (float*)sh;

  // Triangle decode: block k -> (ib <= jb)
  int k = blockIdx.x;
  int r = (int)((sqrtf(8.f * (float)k + 1.f) - 1.f) * 0.5f);
  while ((r + 1) * (r + 2) / 2 <= k) ++r;
  while (r * (r + 1) / 2 > k) --r;
  const int ib = k - r * (r + 1) / 2;
  const int jb = r;
  const bool offd = (ib != jb);

  const int t    = threadIdx.x;
  const int lane = t & 63;
  const int wv   = t >> 6;
  const int col  = lane & 15;
  const int kb   = lane >> 4;

  if (t < BT) {                      // waves 0-1: i-side
    const int ip = ib * BT + t;
    float x2 = p2[2 * ip], y2 = p2[2 * ip + 1];
    float x3 = p3[3 * ip], y3 = p3[3 * ip + 1], z3 = p3[3 * ip + 2];
    build_i(x2, y2, x3, y3, z3, &sh[OFF_A + t * ROWU],
            &sh[OFF_A + BT * ROWU + t * ROWU]);
    shf[OFF_VI + t] = vsrc[ip];
  } else {                           // waves 2-3: j-side
    const int tt = t - BT;
    const int jp = jb * BT + tt;
    float x2 = p2[2 * jp], y2 = p2[2 * jp + 1];
    float x3 = p3[3 * jp], y3 = p3[3 * jp + 1], z3 = p3[3 * jp + 2];
    build_j(x2, y2, x3, y3, z3, &sh[OFF_B + tt * ROWU],
            &sh[OFF_B + BT * ROWU + tt * ROWU]);
    shf[OFF_VJ + tt] = vsrc[jp];
  }
  if (blockIdx.x < 24) vzero[blockIdx.x * 256 + t] = 0.0f;  // zero next-next buf
  __syncthreads();

  // A-fragments + v_i pairs to registers.
  bf16x8 a2f[MI], a3f[MI];
  v2f vi2[MI][2];
#pragma unroll
  for (int mi = 0; mi < MI; ++mi) {
    const int rr = wv * 32 + mi * 16 + col;
    a2f[mi] = *(const bf16x8*)&sh[OFF_A + rr * ROWU + kb * 4];
    a3f[mi] = *(const bf16x8*)&sh[OFF_A + BT * ROWU + rr * ROWU + kb * 4];
#pragma unroll
    for (int p = 0; p < 2; ++p) {
      const int re = wv * 32 + mi * 16 + kb * 4 + 2 * p;
      vi2[mi][p] = (v2f){shf[OFF_VI + re], shf[OFF_VI + re + 1]};
    }
  }

  v2f racc[MI][2];
#pragma unroll
  for (int mi = 0; mi < MI; ++mi) {
    racc[mi][0] = (v2f){0.f, 0.f};
    racc[mi][1] = (v2f){0.f, 0.f};
  }
  const v2f kM100 = (v2f){-100.0f, -100.0f};
  const v2f k200  = (v2f){ 200.0f,  200.0f};
  const v2f kOne  = (v2f){   1.0f,    1.0f};
  const v2f kZero = (v2f){   0.0f,    0.0f};
  const f32x4 z4  = (f32x4){0.f, 0.f, 0.f, 0.f};

#pragma unroll
  for (int tj = 0; tj < JT; ++tj) {
    const int jrow = tj * 16 + col;
    const bf16x8 b2f = *(const bf16x8*)&sh[OFF_B + jrow * ROWU + kb * 4];
    const bf16x8 b3f = *(const bf16x8*)&sh[OFF_B + BT * ROWU + jrow * ROWU + kb * 4];
    const float vjs = shf[OFF_VJ + jrow];
    const v2f vj2 = (v2f){vjs, vjs};
    v2f cacc = (v2f){0.f, 0.f};
#pragma unroll
    for (int mi = 0; mi < MI; ++mi) {
      f32x4 aacc = __builtin_amdgcn_mfma_f32_16x16x32_bf16(a2f[mi], b2f, z4, 0, 0, 0);
      f32x4 bacc = __builtin_amdgcn_mfma_f32_16x16x32_bf16(a3f[mi], b3f, z4, 0, 0, 0);
#pragma unroll
      for (int p = 0; p < 2; ++p) {
        v2f a = (v2f){aacc[2 * p], aacc[2 * p + 1]};
        v2f b = (v2f){bacc[2 * p], bacc[2 * p + 1]};
        v2f ab = __builtin_elementwise_max(a * b, kZero);  // NaN guard near diagonal
        v2f s  = (v2f){__builtin_amdgcn_sqrtf(ab.x), __builtin_amdgcn_sqrtf(ab.y)};
        v2f w  = __builtin_elementwise_fma(a + b, kM100, kOne);
        w = __builtin_elementwise_fma(s, k200, w);
        w = __builtin_elementwise_max(w, kZero);
        racc[mi][p] = __builtin_elementwise_fma(w, vj2, racc[mi][p]);
        if (offd) cacc = __builtin_elementwise_fma(w, vi2[mi][p], cacc);
      }
    }
    if (offd) {  // column contribution: y[J] += S^T v_I  (S symmetric)
      float c = cacc.x + cacc.y;
      c += __shfl_xor(c, 16);
      c += __shfl_xor(c, 32);
      if (lane < 16) atomicAdd(&vdst[jb * BT + tj * 16 + lane], c * RESCALE);
    }
  }

  // Row contribution: reduce across the 16 columns, one atomic per row.
#pragma unroll
  for (int mi = 0; mi < MI; ++mi) {
#pragma unroll
    for (int p = 0; p < 2; ++p) {
      float r0 = racc[mi][p].x, r1 = racc[mi][p].y;
      r0 += __shfl_xor(r0, 1); r0 += __shfl_xor(r0, 2);
      r0 += __shfl_xor(r0, 4); r0 += __shfl_xor(r0, 8);
      r1 += __shfl_xor(r1, 1); r1 += __shfl_xor(r1, 2);
      r1 += __shfl_xor(r1, 4); r1 += __shfl_xor(r1, 8);
      if (col == 0) {
        const int row = ib * BT + wv * 32 + mi * 16 + kb * 4 + 2 * p;
        atomicAdd(&vdst[row],     r0 * RESCALE);
        atomicAdd(&vdst[row + 1], r1 * RESCALE);
      }
    }
  }
}

// out = v / (||v||_2 + 1e-6); each block redundantly computes the norm.
__global__ __launch_bounds__(256) void finalize_kernel(
    const float* __restrict__ v, float* __restrict__ out) {
  const int tid = threadIdx.x;
  float ss = 0.0f;
  for (int k = tid; k < NPTS; k += 256) {
    float x = v[k];
    ss = fmaf(x, x, ss);
  }
  for (int off = 32; off > 0; off >>= 1) ss += __shfl_down(ss, off, 64);
  __shared__ float wsum[4];
  if ((tid & 63) == 0) wsum[tid >> 6] = ss;
  __syncthreads();
  float tot = wsum[0] + wsum[1] + wsum[2] + wsum[3];
  float inv = 1.0f / (sqrtf(tot) + 1e-6f);
  int i = blockIdx.x * 256 + tid;
  out[i] = v[i] * inv;
}

extern "C" void kernel_launch(void* const* d_in, const int* in_sizes, int n_in,
                              void* d_out, int out_size, void* d_ws, size_t ws_size,
                              hipStream_t stream) {
  const float* p2 = (const float*)d_in[0];   // 6144 x 2, float32
  const float* p3 = (const float*)d_in[1];   // 6144 x 3, float32
  float* out = (float*)d_out;                // 6144, float32

  float* w = (float*)d_ws;
  float* buf[3] = { w, w + 8192, w + 16384 };  // v triple-buffer

  prep_kernel<<<NPTS / 256, 256, 0, stream>>>(buf[0], buf[1]);

  for (int k = 0; k < 10; ++k) {
    matvec_kernel<<<NBLK, 256, 0, stream>>>(
        p2, p3, buf[k % 3], buf[(k + 1) % 3], buf[(k + 2) % 3]);
  }

  // after 10 iters, result is in buf[(9+1)%3] == buf[1]
  finalize_kernel<<<NPTS / 256, 256, 0, stream>>>(buf[1], out);
}